// Round 6
// baseline (572.704 us; speedup 1.0000x reference)
//
#include <hip/hip_runtime.h>

typedef unsigned int u32;
typedef unsigned short u16;

#define S_LEN 1024
#define NH 32
#define NKV 8
#define DW 64      // dwords per head row (128 bf16 = 64 u32)
#define NEG_BIG (-1e30f)

typedef __bf16 bf16x8 __attribute__((ext_vector_type(8)));
typedef float f32x4 __attribute__((ext_vector_type(4)));

__device__ __forceinline__ u16 f2bf(float f) {
  u32 u = __builtin_bit_cast(u32, f);
  u += 0x7fffu + ((u >> 16) & 1u);   // RNE
  return (u16)(u >> 16);
}
__device__ __forceinline__ float bflo(u32 u) { return __builtin_bit_cast(float, u << 16); }
__device__ __forceinline__ float bfhi(u32 u) { return __builtin_bit_cast(float, u & 0xffff0000u); }

// global -> LDS direct DMA, 16B per lane. LDS dest is wave-uniform base;
// HW writes lane l at base + l*16 (m97-verified pattern).
__device__ __forceinline__ void gl_lds16(const u16* g, u32* l) {
  __builtin_amdgcn_global_load_lds(
      (__attribute__((address_space(1))) void*)const_cast<u16*>(g),
      (__attribute__((address_space(3))) void*)l, 16, 0, 0);
}

// ---------------------------------------------------------------------------
// Fused fp32 -> bf16 conversion for hs, Wq, Wk, Wv (one launch, 16384 blocks).
// Wq/Wk/Wv land concatenated in Wqkv16 (6144 x 4096 bf16).
// ---------------------------------------------------------------------------
__launch_bounds__(256)
__global__ void cvt_all(const float4* __restrict__ hs, const float4* __restrict__ wq,
                        const float4* __restrict__ wk, const float4* __restrict__ wv,
                        uint4* __restrict__ hs16, uint4* __restrict__ wqkv) {
  const int b = blockIdx.x;
  const float4* src;
  uint4* dst;
  int i;
  if (b < 4096)       { i = b * 256 + threadIdx.x;           src = hs; dst = hs16; }
  else if (b < 12288) { i = (b - 4096) * 256 + threadIdx.x;  src = wq; dst = wqkv; }
  else if (b < 14336) { i = (b - 12288) * 256 + threadIdx.x; src = wk; dst = wqkv + 2097152; }
  else                { i = (b - 14336) * 256 + threadIdx.x; src = wv; dst = wqkv + 2621440; }
  float4 a = src[2 * i], c = src[2 * i + 1];
  uint4 o;
  o.x = (u32)f2bf(a.x) | ((u32)f2bf(a.y) << 16);
  o.y = (u32)f2bf(a.z) | ((u32)f2bf(a.w) << 16);
  o.z = (u32)f2bf(c.x) | ((u32)f2bf(c.y) << 16);
  o.w = (u32)f2bf(c.z) | ((u32)f2bf(c.w) << 16);
  dst[i] = o;
}

// plain fp32 -> bf16 (Wo after the QKV GEMM frees its ws region)
__launch_bounds__(256)
__global__ void cvt_bf16(const float4* __restrict__ in, uint4* __restrict__ out, int n8) {
  int i = blockIdx.x * 256 + threadIdx.x;
  if (i >= n8) return;
  float4 a = in[2 * i], b = in[2 * i + 1];
  uint4 o;
  o.x = (u32)f2bf(a.x) | ((u32)f2bf(a.y) << 16);
  o.y = (u32)f2bf(a.z) | ((u32)f2bf(a.w) << 16);
  o.z = (u32)f2bf(b.x) | ((u32)f2bf(b.y) << 16);
  o.w = (u32)f2bf(b.z) | ((u32)f2bf(b.w) << 16);
  out[i] = o;
}

// ---------------------------------------------------------------------------
// 256x256 double-buffered GEMM, C = A @ B^T (bf16 in).  BK=64, 512 threads =
// 8 waves (2m x 4n), wave tile 128x64 = 8x4 MFMA 16x16x32 frags.
// r6 (T2+T3+T4+T5 per catalog; replaces the ~700TF m97-structure gemm16):
//  * LDS 128 KB: 2 bufs x (A 256x64 + B 256x64) bf16, linear layout for
//    global_load_lds; 16B-slot swizzle via PRE-PERMUTED GLOBAL SOURCE
//    (slot c8 ^ (row&7)) + matching read swizzle (rule #21 both-sides).
//    ds_read_b128 bank pattern: 4*(slot^(col&7)) => 8 bank-quads, 2-way (free).
//  * counted vmcnt: tile kt+2's 8 loads issue after the end-of-tile barrier;
//    tile entry waits vmcnt(8) (next tile's loads stay in flight). vmcnt(0)
//    only on the last tile.
//  * 4 phases/tile, one C-quadrant (mh,nh) x K=64 each: 16 MFMA in
//    setprio(1..0); next-phase fragment ds_reads interleave with MFMA.
//  * raw s_barrier phase fences; sched_barrier(0) pins tile seams (rule #18).
// Fragment layouts identical to the verified gemm16 (A[m][k=quad*8+j],
// B^T[n][k=quad*8+j], C/D row=quad*4+reg col=lane&15).
// MODE: 0 = fp32 C; 2 = QKV triple-route (N=6144: Q|K|V).
// ---------------------------------------------------------------------------
template <int MODE>
__launch_bounds__(512, 2)
__global__ void gemm256(const u16* __restrict__ A, const u16* __restrict__ B,
                        void* __restrict__ C0, void* __restrict__ C1,
                        void* __restrict__ C2, int M, int N, int K) {
  // dwords: bufA0 [0,8192) bufB0 [8192,16384) bufA1 [16384,24576) bufB1 [24576,32768)
  __shared__ u32 L[32768];
  const int tid = threadIdx.x;
  const int lane = tid & 63, w = tid >> 6;
  const int wm = w >> 2, wn = w & 3;
  const int colL = lane & 15, quad = lane >> 4;
  // XCD-rectangle swizzle: 2x4 chunk grid over (gy m-tiles x gx n-tiles)
  const int gx = gridDim.x;
  const int bid = blockIdx.y * gx + blockIdx.x;
  const int CN = gx >> 2, CM = gridDim.y >> 1;
  const int xcd = bid & 7, q = bid >> 3;
  const int cm = xcd >> 2, cn = xcd & 3;
  const int m0 = (cm * CM + q / CN) * 256;
  const int n0 = (cn * CN + q % CN) * 256;

  // staging: thread covers slot s = i*512 + tid; row = s>>3, phys slot = tid&7.
  // source slot pre-permuted: c8s = (tid&7) ^ (row&7), row&7 == (tid>>3)&7.
  const int srow = tid >> 3;                     // 0..63
  const int c8s = (tid & 7) ^ (srow & 7);
  const u16* Asrc = A + (size_t)(m0 + srow) * K + c8s * 8;
  const u16* Bsrc = B + (size_t)(n0 + srow) * K + c8s * 8;
  u32* ldsw = &L[w * 256];                       // wave-uniform; + i*2048 + buf

  auto stage = [&](int kt, int c) {
    const int ko = kt * 64;
    u32* la = ldsw + c * 16384;
#pragma unroll
    for (int i = 0; i < 4; ++i)
      gl_lds16(Asrc + (size_t)i * 64 * K + ko, la + i * 2048);
#pragma unroll
    for (int i = 0; i < 4; ++i)
      gl_lds16(Bsrc + (size_t)i * 64 * K + ko, la + 8192 + i * 2048);
  };

  // read swizzle: logical slot (ks*4+quad) lives at phys slot ^(row&7); row&7 == colL&7
  const int qs[2] = {quad ^ (colL & 7), (quad + 4) ^ (colL & 7)};

  f32x4 acc[8][4] = {};
  bf16x8 a0[4][2], a1[4][2], bb[2][2];

  const int NT = K >> 6;
  stage(0, 0);
  stage(1, 1);

  for (int kt = 0; kt < NT; ++kt) {
    const int c = kt & 1;
    if (kt + 1 < NT) asm volatile("s_waitcnt vmcnt(8)" ::: "memory");
    else             asm volatile("s_waitcnt vmcnt(0)" ::: "memory");
    __builtin_amdgcn_s_barrier();
    __builtin_amdgcn_sched_barrier(0);
    const u32* la = &L[c * 16384];
    const u32* lb = la + 8192;

    // ---- phase 0: read A-half0 (8xb128) + B-pair0 (4); MFMA (mh0,nh0) ----
#pragma unroll
    for (int f = 0; f < 4; ++f)
#pragma unroll
      for (int ks = 0; ks < 2; ++ks)
        a0[f][ks] = *reinterpret_cast<const bf16x8*>(
            &la[(wm * 128 + f * 16 + colL) * 32 + qs[ks] * 4]);
#pragma unroll
    for (int g = 0; g < 2; ++g)
#pragma unroll
      for (int ks = 0; ks < 2; ++ks)
        bb[g][ks] = *reinterpret_cast<const bf16x8*>(
            &lb[(wn * 64 + g * 16 + colL) * 32 + qs[ks] * 4]);
    __builtin_amdgcn_s_setprio(1);
#pragma unroll
    for (int f = 0; f < 4; ++f)
#pragma unroll
      for (int g = 0; g < 2; ++g)
#pragma unroll
        for (int ks = 0; ks < 2; ++ks)
          acc[f][g] = __builtin_amdgcn_mfma_f32_16x16x32_bf16(a0[f][ks], bb[g][ks],
                                                              acc[f][g], 0, 0, 0);
    __builtin_amdgcn_s_setprio(0);
    __builtin_amdgcn_s_barrier();

    // ---- phase 1: read A-half1 (8) + B-pair1 (4); MFMA (mh0,nh1) ----
#pragma unroll
    for (int f = 0; f < 4; ++f)
#pragma unroll
      for (int ks = 0; ks < 2; ++ks)
        a1[f][ks] = *reinterpret_cast<const bf16x8*>(
            &la[(wm * 128 + 64 + f * 16 + colL) * 32 + qs[ks] * 4]);
#pragma unroll
    for (int g = 0; g < 2; ++g)
#pragma unroll
      for (int ks = 0; ks < 2; ++ks)
        bb[g][ks] = *reinterpret_cast<const bf16x8*>(
            &lb[(wn * 64 + (2 + g) * 16 + colL) * 32 + qs[ks] * 4]);
    __builtin_amdgcn_s_setprio(1);
#pragma unroll
    for (int f = 0; f < 4; ++f)
#pragma unroll
      for (int g = 0; g < 2; ++g)
#pragma unroll
        for (int ks = 0; ks < 2; ++ks)
          acc[f][2 + g] = __builtin_amdgcn_mfma_f32_16x16x32_bf16(a0[f][ks], bb[g][ks],
                                                                  acc[f][2 + g], 0, 0, 0);
    __builtin_amdgcn_s_setprio(0);
    __builtin_amdgcn_s_barrier();

    // ---- phase 2: re-read B-pair0 (4); MFMA (mh1,nh0) ----
#pragma unroll
    for (int g = 0; g < 2; ++g)
#pragma unroll
      for (int ks = 0; ks < 2; ++ks)
        bb[g][ks] = *reinterpret_cast<const bf16x8*>(
            &lb[(wn * 64 + g * 16 + colL) * 32 + qs[ks] * 4]);
    __builtin_amdgcn_s_setprio(1);
#pragma unroll
    for (int f = 0; f < 4; ++f)
#pragma unroll
      for (int g = 0; g < 2; ++g)
#pragma unroll
        for (int ks = 0; ks < 2; ++ks)
          acc[4 + f][g] = __builtin_amdgcn_mfma_f32_16x16x32_bf16(a1[f][ks], bb[g][ks],
                                                                  acc[4 + f][g], 0, 0, 0);
    __builtin_amdgcn_s_setprio(0);
    __builtin_amdgcn_s_barrier();

    // ---- phase 3: re-read B-pair1 (4); MFMA (mh1,nh1) ----
#pragma unroll
    for (int g = 0; g < 2; ++g)
#pragma unroll
      for (int ks = 0; ks < 2; ++ks)
        bb[g][ks] = *reinterpret_cast<const bf16x8*>(
            &lb[(wn * 64 + (2 + g) * 16 + colL) * 32 + qs[ks] * 4]);
    __builtin_amdgcn_s_setprio(1);
#pragma unroll
    for (int f = 0; f < 4; ++f)
#pragma unroll
      for (int g = 0; g < 2; ++g)
#pragma unroll
        for (int ks = 0; ks < 2; ++ks)
          acc[4 + f][2 + g] = __builtin_amdgcn_mfma_f32_16x16x32_bf16(a1[f][ks], bb[g][ks],
                                                                      acc[4 + f][2 + g], 0, 0, 0);
    __builtin_amdgcn_s_setprio(0);

    // ---- end-of-tile: all reads of buf c retired globally, then refill it ----
    __builtin_amdgcn_sched_barrier(0);
    __builtin_amdgcn_s_barrier();
    __builtin_amdgcn_sched_barrier(0);
    if (kt + 2 < NT) stage(kt + 2, c);
  }

  // ---- epilogue ----
#pragma unroll
  for (int fm = 0; fm < 8; ++fm)
#pragma unroll
    for (int fn = 0; fn < 4; ++fn)
#pragma unroll
      for (int r = 0; r < 4; ++r) {
        int row = m0 + wm * 128 + fm * 16 + quad * 4 + r;  // C/D: row = quad*4+reg
        int cc  = n0 + wn * 64 + fn * 16 + colL;           //      col = lane&15
        float v = acc[fm][fn][r];
        if constexpr (MODE == 2) {
          if (cc < 4096)      ((u16*)C0)[(size_t)row * 4096 + cc] = f2bf(v);
          else if (cc < 5120) ((u16*)C1)[(size_t)row * 1024 + (cc - 4096)] = f2bf(v);
          else                ((u16*)C2)[(size_t)row * 1024 + (cc - 5120)] = f2bf(v);
        } else {
          ((float*)C0)[(size_t)row * N + cc] = v;
        }
      }
}

// ---------------------------------------------------------------------------
// Fused RoPE: blocks [0,16384) handle Q (1/sqrt(128) folded), rest K.
// ---------------------------------------------------------------------------
__launch_bounds__(256)
__global__ void rope_all(u32* __restrict__ Qb, u32* __restrict__ Kb) {
  int pg = blockIdx.x * 256 + threadIdx.x;
  u32* buf;
  int p, heads;
  float scale;
  if (pg < 4194304) { buf = Qb; p = pg; heads = NH; scale = 0.08838834764831845f; }
  else              { buf = Kb; p = pg - 4194304; heads = NKV; scale = 1.0f; }
  int d2 = p & 63;
  int s = (p / (64 * heads)) % S_LEN;
  float ang = (float)s * expf((float)d2 * -0.14391156831212787f);
  float sn, cs;
  sincosf(ang, &sn, &cs);
  u32 u = buf[p];
  float x0 = bflo(u), x1 = bfhi(u);
  float y0 = (x0 * cs - x1 * sn) * scale;
  float y1 = (x0 * sn + x1 * cs) * scale;
  buf[p] = (u32)f2bf(y0) | ((u32)f2bf(y1) << 16);
}

// ---------------------------------------------------------------------------
// MFMA flash attention (causal GQA, online softmax). Unchanged from r5
// (complementary-pair balance, XCD-locality ids, reg-prefetch, setprio).
// ---------------------------------------------------------------------------
__launch_bounds__(256)
__global__ void attn_kernel(const u32* __restrict__ Qb, const u32* __restrict__ Kb,
                            const u32* __restrict__ Vb, u32* __restrict__ Ob) {
  __shared__ u32 Ks[64 * 64];      // 16 KB
  __shared__ u32 Vt[128 * 32];     // 16 KB
  __shared__ u16 Ps[4][16 * 64];   // 8 KB
  const int tid = threadIdx.x, lane = tid & 63, w = tid >> 6;
  const int col = lane & 15, quad = lane >> 4;
  const int id = blockIdx.x;
  const int kh = id & 7;
  const int j2 = id >> 3;
  const int b = j2 & 1, hin = (j2 >> 1) & 3, pair = j2 >> 3;   // pair 0..7
  const int h = kh * 4 + hin;

  uint4 kpf[4], vpa[2], vpb[2];
  auto prefetch = [&](int t0) {
#pragma unroll
    for (int i = 0; i < 4; ++i) {
      int f = i * 256 + tid;
      int row = f >> 4, c4 = f & 15;
      kpf[i] = *((const uint4*)(Kb + ((size_t)((b * S_LEN + t0 + row) * NKV + kh)) * DW) + c4);
    }
#pragma unroll
    for (int i = 0; i < 2; ++i) {
      int f = i * 256 + tid;
      int kp = f & 31, c8 = f >> 5;
      size_t base0 = ((size_t)((b * S_LEN + t0 + 2 * kp) * NKV + kh)) * DW;
      vpa[i] = *((const uint4*)(Vb + base0) + c8);
      vpb[i] = *((const uint4*)(Vb + base0 + (size_t)NKV * DW) + c8);
    }
  };

  prefetch(0);   // first tile of half 0

  for (int half = 0; half < 2; ++half) {
    const int jt = half ? pair : (15 - pair);   // heavy q-tile first
    const int q0 = jt * 64 + w * 16;

    bf16x8 qf[4];
    {
      const u32* qrow = Qb + ((size_t)((b * S_LEN + q0 + col) * NH + h)) * DW;
#pragma unroll
      for (int dc = 0; dc < 4; ++dc)
        qf[dc] = *reinterpret_cast<const bf16x8*>(qrow + dc * 16 + quad * 4);
    }

    float m_r[4], l_r[4];
    f32x4 oacc[8];
#pragma unroll
    for (int r = 0; r < 4; ++r) { m_r[r] = NEG_BIG; l_r[r] = 0.f; }
#pragma unroll
    for (int dt = 0; dt < 8; ++dt) oacc[dt] = (f32x4){0.f, 0.f, 0.f, 0.f};

    for (int tt = 0; tt <= jt; ++tt) {
      const int t0 = tt * 64;
      __syncthreads();   // readers of prev tile done; drains vmcnt of prefetch
#pragma unroll
      for (int i = 0; i < 4; ++i) {
        int f = i * 256 + tid;
        int row = f >> 4, c4 = f & 15;
        *(uint4*)&Ks[(row * 64 + c4 * 4) ^ ((row & 7) << 2)] = kpf[i];
      }
#pragma unroll
      for (int i = 0; i < 2; ++i) {
        int f = i * 256 + tid;
        int kp = f & 31, c8 = f >> 5;
        u32 a[4] = {vpa[i].x, vpa[i].y, vpa[i].z, vpa[i].w};
        u32 bbv[4] = {vpb[i].x, vpb[i].y, vpb[i].z, vpb[i].w};
#pragma unroll
        for (int t = 0; t < 4; ++t) {
          int d0 = c8 * 8 + 2 * t, d1 = d0 + 1;
          u32 lo = (a[t] & 0xffffu) | (bbv[t] << 16);
          u32 hi = (a[t] >> 16) | (bbv[t] & 0xffff0000u);
          Vt[(d0 * 32 + kp) ^ ((d0 & 7) << 2)] = lo;
          Vt[(d1 * 32 + kp) ^ ((d1 & 7) << 2)] = hi;
        }
      }
      __syncthreads();   // LDS tile published

      if (tt < jt) prefetch(t0 + 64);
      else if (half == 0) prefetch(0);

      f32x4 sacc[4];
#pragma unroll
      for (int kt = 0; kt < 4; ++kt) sacc[kt] = (f32x4){0.f, 0.f, 0.f, 0.f};
      __builtin_amdgcn_s_setprio(1);
#pragma unroll
      for (int dc = 0; dc < 4; ++dc)
#pragma unroll
        for (int kt = 0; kt < 4; ++kt) {
          int key = kt * 16 + col;
          bf16x8 kf = *reinterpret_cast<const bf16x8*>(
              &Ks[(key * 64 + dc * 16 + quad * 4) ^ ((key & 7) << 2)]);
          sacc[kt] = __builtin_amdgcn_mfma_f32_16x16x32_bf16(qf[dc], kf, sacc[kt], 0, 0, 0);
        }
      __builtin_amdgcn_s_setprio(0);

      if (tt == jt) {
#pragma unroll
        for (int kt = 0; kt < 4; ++kt)
#pragma unroll
          for (int r = 0; r < 4; ++r) {
            int tg = t0 + kt * 16 + col;
            int qg = q0 + quad * 4 + r;
            if (tg > qg) sacc[kt][r] = NEG_BIG;
          }
      }

      float mt[4];
#pragma unroll
      for (int r = 0; r < 4; ++r)
        mt[r] = fmaxf(fmaxf(sacc[0][r], sacc[1][r]), fmaxf(sacc[2][r], sacc[3][r]));
#pragma unroll
      for (int off = 1; off < 16; off <<= 1)
#pragma unroll
        for (int r = 0; r < 4; ++r) mt[r] = fmaxf(mt[r], __shfl_xor(mt[r], off));
      float alpha[4], ps[4];
#pragma unroll
      for (int r = 0; r < 4; ++r) {
        float mn = fmaxf(m_r[r], mt[r]);
        alpha[r] = __expf(m_r[r] - mn);
        m_r[r] = mn;
        ps[r] = 0.f;
      }
#pragma unroll
      for (int kt = 0; kt < 4; ++kt)
#pragma unroll
        for (int r = 0; r < 4; ++r) {
          float p = __expf(sacc[kt][r] - m_r[r]);
          u16 pb = f2bf(p);
          int rw = quad * 4 + r;
          Ps[w][(rw * 64 + kt * 16 + col) ^ ((rw & 7) << 3)] = pb;
          ps[r] += bflo((u32)pb);
        }
#pragma unroll
      for (int off = 1; off < 16; off <<= 1)
#pragma unroll
        for (int r = 0; r < 4; ++r) ps[r] += __shfl_xor(ps[r], off);
#pragma unroll
      for (int r = 0; r < 4; ++r) l_r[r] = l_r[r] * alpha[r] + ps[r];
#pragma unroll
      for (int dt = 0; dt < 8; ++dt)
#pragma unroll
        for (int r = 0; r < 4; ++r) oacc[dt][r] *= alpha[r];

      bf16x8 pa[2];
#pragma unroll
      for (int ks = 0; ks < 2; ++ks)
        pa[ks] = *reinterpret_cast<const bf16x8*>(
            &Ps[w][(col * 64 + ks * 32 + quad * 8) ^ ((col & 7) << 3)]);
      __builtin_amdgcn_s_setprio(1);
#pragma unroll
      for (int dt = 0; dt < 8; ++dt) {
        int d = dt * 16 + col;
#pragma unroll
        for (int ks = 0; ks < 2; ++ks) {
          bf16x8 vf = *reinterpret_cast<const bf16x8*>(
              &Vt[(d * 32 + ks * 16 + quad * 4) ^ ((d & 7) << 2)]);
          oacc[dt] = __builtin_amdgcn_mfma_f32_16x16x32_bf16(pa[ks], vf, oacc[dt], 0, 0, 0);
        }
      }
      __builtin_amdgcn_s_setprio(0);
    }

    float invl[4];
#pragma unroll
    for (int r = 0; r < 4; ++r) invl[r] = 1.0f / l_r[r];
    u16* O16 = (u16*)Ob;
#pragma unroll
    for (int dt = 0; dt < 8; ++dt)
#pragma unroll
      for (int r = 0; r < 4; ++r) {
        int qg = q0 + quad * 4 + r;
        int d = dt * 16 + col;
        O16[((size_t)((b * S_LEN + qg) * NH + h)) * 128 + d] = f2bf(oacc[dt][r] * invl[r]);
      }
  }
}

// ---------------------------------------------------------------------------
// fp32 in / fp32 out. Internals bf16. 6 launches.
// d_out: [0,16M) Qb bf16 | [16M,32M) hs16 bf16 (dead before final GEMM write).
// ws (56 MB, serialized reuse):
//   [0,4M) Kb | [4,8M) Vb | [8,56M) Wqkv16 (48 MB, dead after QKV GEMM)
//   then: [8,24M) Ob (attn output) | [24,56M) Wo16 (stream-ordered reuse).
// ---------------------------------------------------------------------------
extern "C" void kernel_launch(void* const* d_in, const int* in_sizes, int n_in,
                              void* d_out, int out_size, void* d_ws, size_t ws_size,
                              hipStream_t stream) {
  const float* hs = (const float*)d_in[0];
  const float* Wq = (const float*)d_in[1];
  const float* Wk = (const float*)d_in[2];
  const float* Wv = (const float*)d_in[3];
  const float* Wo = (const float*)d_in[4];

  u16* Qb   = (u16*)d_out;
  u16* hs16 = (u16*)((char*)d_out + (16u << 20));
  char* ws = (char*)d_ws;
  u16* Kb   = (u16*)ws;
  u16* Vb   = (u16*)(ws + (4u << 20));
  u16* Wqkv = (u16*)(ws + (8u << 20));   // 48 MB, dead after QKV GEMM
  u16* Ob   = (u16*)(ws + (8u << 20));   // 16 MB, written by attn (later)
  u16* Wo16 = (u16*)(ws + (24u << 20));  // 32 MB, written after QKV GEMM

  dim3 blk(256);
  // all fp32->bf16 conversions for stage 1 in one launch
  cvt_all<<<16384, blk, 0, stream>>>((const float4*)hs, (const float4*)Wq,
                                     (const float4*)Wk, (const float4*)Wv,
                                     (uint4*)hs16, (uint4*)Wqkv);
  // fused QKV projection: N = 6144 (Q|K|V), 192 blocks of 512 threads
  gemm256<2><<<dim3(24, 8), dim3(512), 0, stream>>>(hs16, Wqkv, (void*)Qb, (void*)Kb,
                                                    (void*)Vb, 2048, 6144, 4096);
  // fused RoPE on Q (scale folded) and K
  rope_all<<<20480, blk, 0, stream>>>((u32*)Qb, (u32*)Kb);
  // Wo -> bf16 into the now-free upper Wqkv region
  cvt_bf16<<<8192, blk, 0, stream>>>((const float4*)Wo, (uint4*)Wo16, 2097152);
  // causal GQA MFMA flash attention -> Ob (overwrites lower Wqkv region)
  attn_kernel<<<dim3(512), blk, 0, stream>>>((const u32*)Qb, (const u32*)Kb,
                                             (const u32*)Vb, (u32*)Ob);
  // output projection: bf16 x bf16 -> fp32 overwrites d_out
  gemm256<0><<<dim3(16, 8), dim3(512), 0, stream>>>(Ob, Wo16, d_out, nullptr, nullptr,
                                                    2048, 4096, 4096);
}